// Round 14
// baseline (556.558 us; speedup 1.0000x reference)
//
#include <hip/hip_runtime.h>

// ---------------- types ----------------
typedef __bf16 bf16;
typedef __bf16 bf16x4 __attribute__((ext_vector_type(4)));
typedef __bf16 bf16x8 __attribute__((ext_vector_type(8)));
typedef float  f32x4  __attribute__((ext_vector_type(4)));

// Problem constants: b=64, a=8 -> 512 slices, single pass.
#define TT    256
#define FF    256
#define NS    512          // total slices

#define TSTR  40
#define TSZ2  (128 * TSTR)   // 5120 elts: one [128][40] sub-tile

// scheduling primitives for the counted-vmcnt pipeline (T3+T4) + T5 setprio
#define SCHED0 __builtin_amdgcn_sched_barrier(0)
#define BAR    __builtin_amdgcn_s_barrier()
#define WAITVM(N) asm volatile("s_waitcnt vmcnt(" #N ")" ::: "memory")
#define WAITLGKM0 asm volatile("s_waitcnt lgkmcnt(0)" ::: "memory")
#define SP1 __builtin_amdgcn_s_setprio(1)
#define SP0 __builtin_amdgcn_s_setprio(0)

static __device__ inline f32x4 mfma16(bf16x8 a, bf16x8 b, f32x4 c) {
    return __builtin_amdgcn_mfma_f32_16x16x32_bf16(a, b, c, 0, 0, 0);
}

// ---- async global->LDS staging (16B per lane; LDS dest = wave-uniform base + lane*16) ----
typedef const __attribute__((address_space(1))) unsigned int* gp_t;
typedef __attribute__((address_space(3))) unsigned int* lp_t;
static __device__ inline void gll16(const bf16* g, bf16* l) {
    __builtin_amdgcn_global_load_lds((gp_t)g, (lp_t)l, 16, 0, 0);
}

// ---- T2 XOR-swizzle for [rows][32] staging tiles (r10 fix, kept) ----
// stage: source column permute c8 = ((lane&3) ^ ((lane>>3)&3)); read: kg = (lane>>4) ^ ((r15>>1)&3).

// Stage [waves*32][32] bf16 tile: wave wv covers rows wv*32..+32 via 2 vm-ops.
// With 256 threads covers 128 rows (k_temb); with 512 threads covers 256 rows (k_out A).
static __device__ inline void stage128g(const bf16* __restrict__ g, int ld, bf16* __restrict__ l) {
    int lane = threadIdx.x & 63, wv = threadIdx.x >> 6;
    int r = lane >> 2;
    int c8 = ((lane & 3) ^ ((lane >> 3) & 3)) * 8;   // source column permute = s(row)
#pragma unroll
    for (int i = 0; i < 2; i++) {
        int row0 = wv * 32 + i * 16;
        gll16(g + (size_t)(row0 + r) * ld + c8, l + row0 * 32);
    }
}
// 8-wave stage of [128][32] bf16 tile: wave w stages rows [w*16,w*16+16), 1 vm-op/wave.
static __device__ inline void stage8(const bf16* __restrict__ g, int ld, bf16* __restrict__ l) {
    int lane = threadIdx.x & 63, wv = threadIdx.x >> 6;
    int r = lane >> 2;
    int c8 = ((lane & 3) ^ ((lane >> 3) & 3)) * 8;   // source column permute = s(row)
    int row0 = wv * 16;
    gll16(g + (size_t)(row0 + r) * ld + c8, l + row0 * 32);
}
// Swizzled fragment load from [rows][32] staging tile (row0 must be a multiple of 16)
static __device__ inline bf16x8 fragld(const bf16* __restrict__ l, int row0) {
    int lane = threadIdx.x & 63;
    int r15 = lane & 15;
    int kg = (lane >> 4) ^ ((r15 >> 1) & 3);         // read-side XOR undoes source permute
    return *(const bf16x8*)(l + (row0 + r15) * 32 + kg * 8);
}
// Plain strided fragment load (padded derived tiles / lct -- NOT swizzled)
static __device__ inline bf16x8 fragld_s(const bf16* __restrict__ l, int row0, int stride) {
    int lane = threadIdx.x & 63;
    return *(const bf16x8*)(l + (row0 + (lane & 15)) * stride + (lane >> 4) * 8);
}

// ---------------- small prep kernels ----------------
__global__ __launch_bounds__(256) void k_cvt(const float4* __restrict__ src, bf16* __restrict__ dst) {
    int i = blockIdx.x * 256 + threadIdx.x;
    float4 v = src[i];
    bf16x4 o;
    o[0] = (__bf16)v.x; o[1] = (__bf16)v.y; o[2] = (__bf16)v.z; o[3] = (__bf16)v.w;
    *(bf16x4*)(dst + (size_t)i * 4) = o;
}

__global__ __launch_bounds__(256) void k_mish(const float4* __restrict__ src, bf16* __restrict__ dst) {
    int i = blockIdx.x * 256 + threadIdx.x;
    float4 v = src[i];
    float in[4] = {v.x, v.y, v.z, v.w};
    bf16x4 o;
#pragma unroll
    for (int j = 0; j < 4; j++) {
        float sp = log1pf(__expf(in[j]));
        o[j] = (__bf16)(in[j] * tanhf(sp));
    }
    *(bf16x4*)(dst + (size_t)i * 4) = o;
}

// x [s][f][t] fp32 -> xT [s][t][f] bf16; grid NS*16
__global__ __launch_bounds__(256) void k_xpose(const float* __restrict__ x, bf16* __restrict__ xT) {
    __shared__ float tile[64][65];
    int bid = blockIdx.x;
    int s  = bid >> 4;
    int f0 = ((bid >> 2) & 3) * 64;
    int t0 = (bid & 3) * 64;
    int tid = threadIdx.x;
    int rr = tid >> 4;
    int cc = (tid & 15) * 4;
    const float* xp = x + ((size_t)(s * FF + f0)) * TT + t0;
#pragma unroll
    for (int i = 0; i < 4; i++) {
        int r = i * 16 + rr;
        float4 v = *(const float4*)(xp + (size_t)r * TT + cc);
        tile[r][cc] = v.x; tile[r][cc + 1] = v.y; tile[r][cc + 2] = v.z; tile[r][cc + 3] = v.w;
    }
    __syncthreads();
    bf16* op = xT + ((size_t)(s * TT + t0)) * FF + f0;
#pragma unroll
    for (int i = 0; i < 4; i++) {
        int tr = i * 16 + rr;
        bf16x4 o;
        o[0] = (__bf16)tile[cc][tr];     o[1] = (__bf16)tile[cc + 1][tr];
        o[2] = (__bf16)tile[cc + 2][tr]; o[3] = (__bf16)tile[cc + 3][tr];
        *(bf16x4*)(op + (size_t)tr * FF + cc) = o;
    }
}

// ---------------- temb GEMM: tembT[o][s] = w_time[o][:] . mish[s][:] + b_time[o] ----------------
__global__ __launch_bounds__(256) void k_temb(const bf16* __restrict__ wt, const bf16* __restrict__ mish,
                                              const float* __restrict__ bt, float* __restrict__ tembT) {
    __shared__ bf16 lA[128 * 32];
    __shared__ bf16 lB[128 * 32];
    int o0 = blockIdx.x * 128, s0 = blockIdx.y * 128;
    int tid = threadIdx.x, wv = tid >> 6, lane = tid & 63, qd = lane >> 4, c = lane & 15;
    f32x4 acc[2][8] = {};
    for (int k0 = 0; k0 < 256; k0 += 32) {
        __syncthreads();
        stage128g(wt + (size_t)o0 * 256 + k0, 256, lA);
        stage128g(mish + (size_t)s0 * 256 + k0, 256, lB);
        __syncthreads();
        bf16x8 a0 = fragld(lA, wv * 32), a1 = fragld(lA, wv * 32 + 16);
#pragma unroll
        for (int nt = 0; nt < 8; nt++) {
            bf16x8 b = fragld(lB, nt * 16);
            acc[0][nt] = mfma16(a0, b, acc[0][nt]);
            acc[1][nt] = mfma16(a1, b, acc[1][nt]);
        }
    }
#pragma unroll
    for (int mt = 0; mt < 2; mt++)
#pragma unroll
        for (int nt = 0; nt < 8; nt++)
#pragma unroll
            for (int r = 0; r < 4; r++) {
                int o = o0 + wv * 32 + mt * 16 + qd * 4 + r;
                int s = s0 + nt * 16 + c;
                tembT[(size_t)o * 512 + s] = acc[mt][nt][r] + bt[o];
            }
}

// ---------------- fused qkv + attention per (s, h) -- unchanged from r12/r13 ----------------
#define LXF(i)  ((bf16*)(smem + (size_t)(i) * 8192))
#define LWAF(i) ((bf16*)(smem + 24576 + (size_t)(i) * 8192))
#define LWBF(i) ((bf16*)(smem + 49152 + (size_t)(i) * 8192))
#define KV_STAGE(st) { int _b = (st) % 3; stage8(xh + (st) * 32, 256, LXF(_b)); \
                       stage8(Wk + (st) * 32, 256, LWAF(_b)); stage8(Wv + (st) * 32, 256, LWBF(_b)); }
#define Q_STAGE(st)  { int _b = (st) % 3; stage8(xh2 + (st) * 32, 256, LXF(_b)); \
                       stage8(Wq + (st) * 32, 256, LWAF(_b)); }
__global__ __launch_bounds__(512, 2) void k_fused(const bf16* __restrict__ wqkv, const bf16* __restrict__ xT,
                                                  const float* __restrict__ tembT, bf16* __restrict__ midT) {
    __shared__ __align__(16) char smem[156160];
    float* ls  = (float*)(smem + 73728);
    bf16*  lk  = (bf16*)(smem + 74240);
    bf16*  lct = (bf16*)(smem + 74240);
    bf16*  lv  = (bf16*)(smem + 115200);
    bf16*  lq  = (bf16*)(smem + 115200);

    int b = blockIdx.x;
    int w = (b & 7) * (4 * NS / 8) + (b >> 3);   // XCD chunking, 4*NS % 8 == 0
    int s = w >> 2, h = w & 3;
    int tid = threadIdx.x, wv = tid >> 6, lane = tid & 63, qd = lane >> 4, c = lane & 15;
    int wa = wv >> 1;        // A-chunk: rows wa*32 .. +32
    int wb = wv & 1;         // B-half:  cols wb*64 .. +64
    const bf16* xs = xT + (size_t)s * (TT * FF);
    const bf16* Wq = wqkv + (size_t)(h * 128) * 256;
    const bf16* Wk = wqkv + (size_t)(512 + h * 128) * 256;
    const bf16* Wv = wqkv + (size_t)(1024 + h * 128) * 256;

    if (tid < 128) ls[tid] = 0.f;   // ordered vs atomics by the first loop barrier

    f32x4 cacc[2][4] = {};   // ct: row e = wa*32 + ai*16 + qd*4 + r, col d = wb*64 + nt*16 + c

    float tbk2[4], tbv2[4];
#pragma unroll
    for (int nt = 0; nt < 4; nt++) {
        int ch = wb * 64 + nt * 16 + c;
        tbk2[nt] = tembT[(size_t)(512 + h * 128 + ch) * 512 + s];
        tbv2[nt] = tembT[(size_t)(1024 + h * 128 + ch) * 512 + s];
    }

    for (int th = 0; th < 2; th++) {
        // ---- kv GEMM for t-half th: batch-2 pairs, 3 bufs, counted vmcnt (3 ops/wave/step) ----
        f32x4 kacc[2][4] = {}, vacc[2][4] = {};
        const bf16* xh = xs + (size_t)th * 128 * 256;
        KV_STAGE(0); SCHED0; KV_STAGE(1); SCHED0; KV_STAGE(2); SCHED0;
#pragma unroll
        for (int p = 0; p < 4; p++) {
            if (p == 3) { WAITVM(0); } else { WAITVM(3); }
            SCHED0; BAR; SCHED0;
            SP1;
#pragma unroll
            for (int u = 0; u < 2; u++) {
                int tb = (2 * p + u) % 3;
                bf16x8 a0 = fragld(LXF(tb), wa * 32);        // A = x rows t
                bf16x8 a1 = fragld(LXF(tb), wa * 32 + 16);
#pragma unroll
                for (int nt = 0; nt < 4; nt++) {
                    int row = wb * 64 + nt * 16;
                    bf16x8 bk = fragld(LWAF(tb), row);
                    bf16x8 bv = fragld(LWBF(tb), row);
                    kacc[0][nt] = mfma16(a0, bk, kacc[0][nt]);
                    kacc[1][nt] = mfma16(a1, bk, kacc[1][nt]);
                    vacc[0][nt] = mfma16(a0, bv, vacc[0][nt]);
                    vacc[1][nt] = mfma16(a1, bv, vacc[1][nt]);
                }
            }
            SP0;
            SCHED0; BAR; SCHED0;
            if (p == 0) { KV_STAGE(3); KV_STAGE(4); }
            else if (p == 1) { KV_STAGE(5); KV_STAGE(6); }
            else if (p == 2) { KV_STAGE(7); }
            SCHED0;
        }
        // store exp(k+bias) / (v+bias) to padded tiles [tc=wa][128 ch][40 t]; colsum reduce.
        {
#pragma unroll
            for (int nt = 0; nt < 4; nt++) {
                int ch = wb * 64 + nt * 16 + c;
                float ps = 0.f;
                bf16x4 ok0, ok1, ov0, ov1;
#pragma unroll
                for (int r = 0; r < 4; r++) {
                    bf16 e0 = (__bf16)__expf(kacc[0][nt][r] + tbk2[nt]);
                    bf16 e1 = (__bf16)__expf(kacc[1][nt][r] + tbk2[nt]);
                    ok0[r] = e0; ok1[r] = e1; ps += (float)e0 + (float)e1;
                    ov0[r] = (__bf16)(vacc[0][nt][r] + tbv2[nt]);
                    ov1[r] = (__bf16)(vacc[1][nt][r] + tbv2[nt]);
                }
                int ad = wa * TSZ2 + ch * TSTR + qd * 4;
                *(bf16x4*)(lk + ad)      = ok0;
                *(bf16x4*)(lk + ad + 16) = ok1;
                *(bf16x4*)(lv + ad)      = ov0;
                *(bf16x4*)(lv + ad + 16) = ov1;
                ps += __shfl_xor(ps, 16);
                ps += __shfl_xor(ps, 32);
                if (qd == 0) atomicAdd(&ls[ch], ps);
            }
        }
        __syncthreads();   // lk/lv visible
        // ---- phase 2: cacc += v · expk over this half's 4 t-sub-tiles ----
        SP1;
#pragma unroll
        for (int tc = 0; tc < 4; tc++) {
            bf16x8 a0 = fragld_s(lv + tc * TSZ2, wa * 32, TSTR);       // A = v rows e
            bf16x8 a1 = fragld_s(lv + tc * TSZ2, wa * 32 + 16, TSTR);
#pragma unroll
            for (int nt = 0; nt < 4; nt++) {
                bf16x8 kf = fragld_s(lk + tc * TSZ2, wb * 64 + nt * 16, TSTR);
                cacc[0][nt] = mfma16(a0, kf, cacc[0][nt]);
                cacc[1][nt] = mfma16(a1, kf, cacc[1][nt]);
            }
        }
        SP0;
        __syncthreads();   // done reading lk/lv before next half overwrites
    }

    // q half-0 prologue first: its latency hides under the ct write (2 ops/wave/step)
    {
        const bf16* xh2 = xs;
        Q_STAGE(0); SCHED0; Q_STAGE(1); SCHED0; Q_STAGE(2); SCHED0;
    }

    // ---- ct -> lct [e][136 d], scaled by 1/sum (lk dead; ls complete) ----
#pragma unroll
    for (int ai = 0; ai < 2; ai++)
#pragma unroll
        for (int nt = 0; nt < 4; nt++) {
            int d = wb * 64 + nt * 16 + c;
            float rv = 1.0f / ls[d];
#pragma unroll
            for (int r = 0; r < 4; r++)
                lct[(wa * 32 + ai * 16 + qd * 4 + r) * 136 + d] = (__bf16)(cacc[ai][nt][r] * rv);
        }
    WAITLGKM0;           // lct visible WITHOUT draining the q prefetch
    SCHED0; BAR; SCHED0;

    // ---- q GEMM + out per t-half: batch-2 pairs ----
    float tbq2[2][4];
#pragma unroll
    for (int ai = 0; ai < 2; ai++)
#pragma unroll
        for (int r = 0; r < 4; r++)
            tbq2[ai][r] = tembT[(size_t)(h * 128 + wa * 32 + ai * 16 + qd * 4 + r) * 512 + s];
    for (int th = 0; th < 2; th++) {
        f32x4 qacc[2][4] = {};
        const bf16* xh2 = xs + (size_t)th * 128 * 256;
        if (th == 1) { Q_STAGE(0); SCHED0; Q_STAGE(1); SCHED0; Q_STAGE(2); SCHED0; }
#pragma unroll
        for (int p = 0; p < 4; p++) {
            if (p == 3) { WAITVM(0); } else { WAITVM(2); }   // th=1: older midT stores drain first (safe)
            SCHED0; BAR; SCHED0;
            SP1;
#pragma unroll
            for (int u = 0; u < 2; u++) {
                int tb = (2 * p + u) % 3;
                bf16x8 a0 = fragld(LWAF(tb), wa * 32);        // A = Wq rows d
                bf16x8 a1 = fragld(LWAF(tb), wa * 32 + 16);
#pragma unroll
                for (int nt = 0; nt < 4; nt++) {
                    bf16x8 xf = fragld(LXF(tb), wb * 64 + nt * 16);
                    qacc[0][nt] = mfma16(a0, xf, qacc[0][nt]);
                    qacc[1][nt] = mfma16(a1, xf, qacc[1][nt]);
                }
            }
            SP0;
            SCHED0; BAR; SCHED0;
            if (p == 0) { Q_STAGE(3); Q_STAGE(4); }
            else if (p == 1) { Q_STAGE(5); Q_STAGE(6); }
            else if (p == 2) { Q_STAGE(7); }
            SCHED0;
        }
        // store q (+bias) to padded tiles [dc=wa][128 t][40 d-within]
        {
#pragma unroll
            for (int nt = 0; nt < 4; nt++) {
                int t = wb * 64 + nt * 16 + c;
#pragma unroll
                for (int ai = 0; ai < 2; ai++) {
                    bf16x4 oq;
#pragma unroll
                    for (int r = 0; r < 4; r++) oq[r] = (__bf16)(qacc[ai][nt][r] + tbq2[ai][r]);
                    *(bf16x4*)(lq + wa * TSZ2 + t * TSTR + ai * 16 + qd * 4) = oq;
                }
            }
        }
        __syncthreads();   // lq visible
        // ---- 3b: out[e][t-half] = sum_d ct[e][d] q[d][t] ----
        f32x4 oacc[2][4] = {};
        SP1;
#pragma unroll
        for (int dd = 0; dd < 4; dd++) {
            bf16x8 a0 = fragld_s(lct + dd * 32, wa * 32, 136);        // A = ct rows e
            bf16x8 a1 = fragld_s(lct + dd * 32, wa * 32 + 16, 136);
#pragma unroll
            for (int nt = 0; nt < 4; nt++) {
                bf16x8 qf = fragld_s(lq + dd * TSZ2, wb * 64 + nt * 16, TSTR);
                oacc[0][nt] = mfma16(a0, qf, oacc[0][nt]);
                oacc[1][nt] = mfma16(a1, qf, oacc[1][nt]);
            }
        }
        SP0;
        // epilogue: midT[s][t][h*128 + e], bf16x4 along e
#pragma unroll
        for (int nt = 0; nt < 4; nt++)
#pragma unroll
            for (int ai = 0; ai < 2; ai++) {
                int t = th * 128 + wb * 64 + nt * 16 + c;
                int e = wa * 32 + ai * 16 + qd * 4;
                bf16x4 o;
#pragma unroll
                for (int r = 0; r < 4; r++) o[r] = (__bf16)oacc[ai][nt][r];
                *(bf16x4*)(midT + ((size_t)s * 256 + t) * 512 + h * 128 + e) = o;
            }
        __syncthreads();   // 3b reads of lq done before next half overwrites
    }
}

// ---------------- final conv -- v2: 512 threads, M=256, 2 blocks/CU ----------------
// y[s][o][t] = w_out[o][:] . mid[:][t] + b_out[o]. Grid 2*NS (t-halves), XCD swizzle.
// vs r12 (256 thr, M=128, 98KB LDS -> 1 block/CU = 4 waves/CU, 2048 blocks = 8 rounds):
//  - 8 waves, 4x2 tiling (wave owns 64 o x 64 t, acc[4][4]=64 regs, 8 reads/step vs 10)
//  - M=256 full o-range: halves W re-staging (each slice's W staged 2x not 4x)
//  - LDS 3x(16+8)KB = 72KB -> 2 blocks/CU (16 waves/CU); 1024 blocks = 4 rounds, 2-deep
//    cross-block overlap hides the barrier-period latency the 1-block config exposed.
__global__ __launch_bounds__(512, 4) void k_out(const bf16* __restrict__ wo, const bf16* __restrict__ midT,
                                                const float* __restrict__ bo, float* __restrict__ y) {
    __shared__ bf16 lA[3][256 * 32];   // W tiles [256 o][32 f]
    __shared__ bf16 lB[3][128 * 32];   // mid tiles [128 t][32 f]
    int b = blockIdx.x;
    int w = (b & 7) * (2 * NS / 8) + (b >> 3);    // XCD chunking, 2*NS % 8 == 0
    int s = w >> 1, t0 = (w & 1) * 128;
    int tid = threadIdx.x, wv = tid >> 6, lane = tid & 63, qd = lane >> 4, c = lane & 15;
    int wa = wv >> 1;   // o-chunk: rows wa*64 .. +64
    int wb = wv & 1;    // t-half within block: cols wb*64 .. +64
    const bf16* ms = midT + (size_t)s * 131072 + (size_t)t0 * 512;
    f32x4 acc[4][4] = {};
    // prologue: steps 0,1,2 (3 vm-ops/wave/step: 2 for A[256][32], 1 for B[128][32])
    stage128g(wo, 512, lA[0]);      stage8(ms, 512, lB[0]);      SCHED0;
    stage128g(wo + 32, 512, lA[1]); stage8(ms + 32, 512, lB[1]); SCHED0;
    stage128g(wo + 64, 512, lA[2]); stage8(ms + 64, 512, lB[2]); SCHED0;
#pragma unroll
    for (int p = 0; p < 8; p++) {
        if (p == 7) { WAITVM(0); } else { WAITVM(3); }   // steps 2p,2p+1 landed; 2p+2 in flight
        SCHED0; BAR; SCHED0;
        SP1;
#pragma unroll
        for (int u = 0; u < 2; u++) {
            int tb = (2 * p + u) % 3;
            bf16x8 a[4];
#pragma unroll
            for (int ai = 0; ai < 4; ai++) a[ai] = fragld(lA[tb], wa * 64 + ai * 16);
#pragma unroll
            for (int nt = 0; nt < 4; nt++) {
                bf16x8 bfr = fragld(lB[tb], wb * 64 + nt * 16);
#pragma unroll
                for (int ai = 0; ai < 4; ai++)
                    acc[ai][nt] = mfma16(a[ai], bfr, acc[ai][nt]);
            }
        }
        SP0;
        SCHED0; BAR; SCHED0;
        {
            int s1 = 2 * p + 3;
            if (s1 < 16)     { stage128g(wo + s1 * 32, 512, lA[s1 % 3]);
                               stage8(ms + s1 * 32, 512, lB[s1 % 3]); }
            if (s1 + 1 < 16) { stage128g(wo + (s1 + 1) * 32, 512, lA[(s1 + 1) % 3]);
                               stage8(ms + (s1 + 1) * 32, 512, lB[(s1 + 1) % 3]); }
        }
        SCHED0;
    }
    // epilogue: o = wa*64 + ai*16 + qd*4 + r, t = t0 + wb*64 + nt*16 + c (16-lane 64B runs)
    float bb[4][4];
#pragma unroll
    for (int ai = 0; ai < 4; ai++)
#pragma unroll
        for (int r = 0; r < 4; r++)
            bb[ai][r] = bo[wa * 64 + ai * 16 + qd * 4 + r];
#pragma unroll
    for (int ai = 0; ai < 4; ai++)
#pragma unroll
        for (int nt = 0; nt < 4; nt++)
#pragma unroll
            for (int r = 0; r < 4; r++) {
                int o = wa * 64 + ai * 16 + qd * 4 + r;
                int t = t0 + wb * 64 + nt * 16 + c;
                y[((size_t)(s * 256 + o)) * 256 + t] = acc[ai][nt][r] + bb[ai][r];
            }
}

// ---------------- launch ----------------
extern "C" void kernel_launch(void* const* d_in, const int* in_sizes, int n_in,
                              void* d_out, int out_size, void* d_ws, size_t ws_size,
                              hipStream_t stream) {
    const float* x      = (const float*)d_in[0];
    const float* time_  = (const float*)d_in[1];
    const float* w_qkv  = (const float*)d_in[2];
    const float* w_time = (const float*)d_in[3];
    const float* b_time = (const float*)d_in[4];
    const float* w_out  = (const float*)d_in[5];
    const float* b_out  = (const float*)d_in[6];
    float* y = (float*)d_out;
    char* ws = (char*)d_ws;

    // Workspace (single pass):
    bf16*  wqkv_bf  = (bf16*)(ws + 0);            //   786432 B
    bf16*  wtime_bf = (bf16*)(ws + 786432);       //   786432 B
    bf16*  wout_bf  = (bf16*)(ws + 1572864);      //   262144 B
    bf16*  mish_bf  = (bf16*)(ws + 1835008);      //   262144 B
    float* tembT    = (float*)(ws + 2097152);     //  3145728 B  [1536][512]
    bf16*  xT       = (bf16*)(ws + 5242880);      // 67108864 B  (all 512 slices)
    bf16*  midT     = (bf16*)(ws + 72351744);     // 134217728 B (ends 206569472 < 512 MiB)

    // prep
    k_cvt<<<384, 256, 0, stream>>>((const float4*)w_qkv, wqkv_bf);
    k_cvt<<<384, 256, 0, stream>>>((const float4*)w_time, wtime_bf);
    k_cvt<<<128, 256, 0, stream>>>((const float4*)w_out, wout_bf);
    k_mish<<<128, 256, 0, stream>>>((const float4*)time_, mish_bf);
    k_temb<<<dim3(12, 4), 256, 0, stream>>>(wtime_bf, mish_bf, b_time, tembT);

    // single-pass pipeline
    k_xpose<<<NS * 16, 256, 0, stream>>>(x, xT);
    k_fused<<<NS * 4, 512, 0, stream>>>(wqkv_bf, xT, tembT, midT);
    k_out<<<2 * NS, 512, 0, stream>>>(wout_bf, midT, b_out, y);
}